// Round 3
// baseline (121.689 us; speedup 1.0000x reference)
//
#include <hip/hip_runtime.h>
#include <hip/hip_bf16.h>

#define NROWS 8192
#define MCOLS 8192
#define DK    64

typedef __attribute__((ext_vector_type(8))) short bf16x8;
typedef __attribute__((ext_vector_type(4))) float f32x4;

// ws layout (4.25 MB): Xh@0, Xl@1M, Zh@2M, Zl@3M (bf16 [8192][64] row-major),
// hx@4M (8192 f32 = 0.5*|Xs|^2), hz@4M+32K
#define WS_XH 0
#define WS_XL (1u << 20)
#define WS_ZH (2u << 20)
#define WS_ZL (3u << 20)
#define WS_HX (4u << 20)
#define WS_HZ ((4u << 20) + 32768u)
#define WS_NEED ((size_t)(4u << 20) + 65536u)

__device__ __forceinline__ float softplus_f(float x) {
    // matches jnp.where(x > 36, x, log1p(exp(min(x, 36))))
    return x > 36.0f ? x : log1pf(expf(fminf(x, 36.0f)));
}

__device__ __forceinline__ unsigned short to_bf16(float x) {
    unsigned int u = __float_as_uint(x);
    u += 0x7fffu + ((u >> 16) & 1u);   // round-to-nearest-even
    return (unsigned short)(u >> 16);
}
__device__ __forceinline__ float from_bf16(unsigned short h) {
    return __uint_as_float(((unsigned int)h) << 16);
}

// ---------------- prep: scale by w=1/softplus(l), split bf16 hi/lo, norms ----
// 131072 threads: one per (matrix, row, kchunk-of-8). X first 65536, then Z.
__global__ void rbf_prep(const float* __restrict__ X, const float* __restrict__ Z,
                         const float* __restrict__ lraw, char* __restrict__ ws) {
    int tid = blockIdx.x * 256 + threadIdx.x;   // 0..131071
    bool isZ = tid >= 65536;                    // block-uniform (65536 % 256 == 0)
    int t = tid & 65535;
    int row = t >> 3;
    int kc = t & 7;
    const float* src = (isZ ? Z : X) + (size_t)row * DK + kc * 8;
    float4 v0 = *(const float4*)(src);
    float4 v1 = *(const float4*)(src + 4);
    float f[8] = {v0.x, v0.y, v0.z, v0.w, v1.x, v1.y, v1.z, v1.w};
    bf16x8 hv, lv;
    float sq = 0.0f;
    #pragma unroll
    for (int j = 0; j < 8; ++j) {
        float w = 1.0f / softplus_f(lraw[kc * 8 + j]);
        float fv = f[j] * w;
        sq += fv * fv;
        unsigned short h = to_bf16(fv);
        hv[j] = (short)h;
        lv[j] = (short)to_bf16(fv - from_bf16(h));
    }
    sq += __shfl_xor(sq, 1);
    sq += __shfl_xor(sq, 2);
    sq += __shfl_xor(sq, 4);
    char* base = ws + (isZ ? WS_ZH : WS_XH);
    *(bf16x8*)(base + (size_t)row * 128 + kc * 16) = hv;
    *(bf16x8*)(base + (1u << 20) + (size_t)row * 128 + kc * 16) = lv;
    if (kc == 0) {
        float* nrm = (float*)(ws + (isZ ? WS_HZ : WS_HX));
        nrm[row] = 0.5f * sq;
    }
}

// ---------------- main: no LDS, no barriers; 1 wave = one 64x64 tile --------
// Fragments loaded straight from the L2/L3-resident bf16 panels. Waves run
// free so stores issue continuously (fixes the ~57% store duty cycle of the
// phase-locked LDS version).
__launch_bounds__(256, 4)
__global__ void rbf_main(const float* __restrict__ sraw, const char* __restrict__ ws,
                         float* __restrict__ out) {
    // XCD-bijective swizzle: 4096 blocks, 8 XCDs, 512 contiguous per XCD
    int bid = blockIdx.x;
    int s = (bid & 7) * 512 + (bid >> 3);
    int tR = s >> 6, tC = s & 63;

    const float sf = softplus_f(sraw[0]);
    const int lane = threadIdx.x & 63;
    const int wid  = threadIdx.x >> 6;
    const int wr = wid >> 1, wc = wid & 1;
    const int lr = lane & 15;    // A-row / B-col within fragment
    const int lg = lane >> 4;    // k-group

    const char* Xh = ws + WS_XH;
    const char* Zh = ws + WS_ZH;
    const float* hx = (const float*)(ws + WS_HX);
    const float* hz = (const float*)(ws + WS_HZ);

    const int arow0 = tR * 128 + wr * 64;
    const int bcol0 = tC * 128 + wc * 64;

    f32x4 acc[4][4];
    #pragma unroll
    for (int a = 0; a < 4; ++a)
        #pragma unroll
        for (int b = 0; b < 4; ++b) acc[a][b] = f32x4{0.f, 0.f, 0.f, 0.f};

    // cross = Ah*Bh + Ah*Bl + Al*Bh (fp32 accum), K=64 as 2 chunks of 32
    #pragma unroll
    for (int pass = 0; pass < 3; ++pass) {
        const char* Ap = Xh + ((pass == 2) ? (1u << 20) : 0);  // Al on pass 2
        const char* Bp = Zh + ((pass == 1) ? (1u << 20) : 0);  // Bl on pass 1
        #pragma unroll
        for (int ks = 0; ks < 2; ++ks) {
            const int ko = lg * 16 + ks * 64;   // byte offset in 128 B row
            bf16x8 af[4], bfr[4];
            #pragma unroll
            for (int mi = 0; mi < 4; ++mi)
                af[mi] = *(const bf16x8*)(Ap + (size_t)(arow0 + mi * 16 + lr) * 128 + ko);
            #pragma unroll
            for (int ni = 0; ni < 4; ++ni)
                bfr[ni] = *(const bf16x8*)(Bp + (size_t)(bcol0 + ni * 16 + lr) * 128 + ko);
            #pragma unroll
            for (int mi = 0; mi < 4; ++mi)
                #pragma unroll
                for (int ni = 0; ni < 4; ++ni)
                    acc[mi][ni] = __builtin_amdgcn_mfma_f32_16x16x32_bf16(
                        af[mi], bfr[ni], acc[mi][ni], 0, 0, 0);
        }
    }

    // epilogue: out = sf * exp(cross - 0.5|x|^2 - 0.5|z|^2)
    #pragma unroll
    for (int mi = 0; mi < 4; ++mi) {
        int row0 = arow0 + mi * 16 + lg * 4;     // C/D: col=lane&15, row=lg*4+j
        float4 hxv = *(const float4*)(hx + row0);
        float hxa[4] = {hxv.x, hxv.y, hxv.z, hxv.w};
        #pragma unroll
        for (int ni = 0; ni < 4; ++ni) {
            int col = bcol0 + ni * 16 + lr;
            float hzv = hz[col];
            size_t obase = (size_t)row0 * MCOLS + col;
            #pragma unroll
            for (int j = 0; j < 4; ++j)
                out[obase + (size_t)j * MCOLS] = sf * __expf(acc[mi][ni][j] - hxa[j] - hzv);
        }
    }
}

// ---------------- fallback (R2 kernel) if ws is too small -------------------
__launch_bounds__(512, 4)
__global__ void rbf_fused(const float* __restrict__ X, const float* __restrict__ Z,
                          const float* __restrict__ lraw, const float* __restrict__ sraw,
                          float* __restrict__ out) {
    __shared__ __align__(16) char smem[65536];
    __shared__ float hxz[256];
    __shared__ float wsc[DK];
    __shared__ float sigf_s;

    const int tid = threadIdx.x;
    const int tR = blockIdx.y;
    const int tC = blockIdx.x;

    if (tid < DK) wsc[tid] = 1.0f / softplus_f(lraw[tid]);
    if (tid == 511) sigf_s = softplus_f(sraw[0]);
    __syncthreads();

    #pragma unroll
    for (int i = 0; i < 4; ++i) {
        int rfull = i * 64 + (tid >> 3);
        int r = rfull & 127;
        int kc = tid & 7;
        bool isB = rfull >= 128;
        const float* src = isB ? (Z + (size_t)(tC * 128 + r) * DK + kc * 8)
                               : (X + (size_t)(tR * 128 + r) * DK + kc * 8);
        float4 v0 = *(const float4*)(src);
        float4 v1 = *(const float4*)(src + 4);
        float f[8] = {v0.x, v0.y, v0.z, v0.w, v1.x, v1.y, v1.z, v1.w};
        bf16x8 hv, lv;
        float sq = 0.0f;
        #pragma unroll
        for (int j = 0; j < 8; ++j) {
            float fv = f[j] * wsc[kc * 8 + j];
            sq += fv * fv;
            unsigned short h = to_bf16(fv);
            hv[j] = (short)h;
            lv[j] = (short)to_bf16(fv - from_bf16(h));
        }
        sq += __shfl_xor(sq, 1);
        sq += __shfl_xor(sq, 2);
        sq += __shfl_xor(sq, 4);
        if (kc == 0) hxz[rfull] = 0.5f * sq;
        int halfOff = isB ? 32768 : 0;
        int byteOff = r * 128 + ((kc * 16) ^ ((r & 7) << 4));
        *(bf16x8*)(smem + halfOff + byteOff) = hv;
        *(bf16x8*)(smem + halfOff + 16384 + byteOff) = lv;
    }
    __syncthreads();

    const int lane = tid & 63;
    const int wid  = tid >> 6;
    const int wr = wid >> 1;
    const int wc = wid & 1;
    const int lr = lane & 15;
    const int lg = lane >> 4;
    const int swz = (lr & 7) << 4;

    f32x4 acc[2][4];
    #pragma unroll
    for (int a = 0; a < 2; ++a)
        #pragma unroll
        for (int b = 0; b < 4; ++b) acc[a][b] = f32x4{0.f, 0.f, 0.f, 0.f};

    #pragma unroll
    for (int pass = 0; pass < 3; ++pass) {
        const char* Ap = smem + ((pass == 2) ? 16384 : 0);
        const char* Bp = smem + 32768 + ((pass == 1) ? 16384 : 0);
        #pragma unroll
        for (int ks = 0; ks < 2; ++ks) {
            int kb = ((lg * 16 + ks * 64) ^ swz);
            bf16x8 af[2], bfr[4];
            #pragma unroll
            for (int mi = 0; mi < 2; ++mi)
                af[mi] = *(const bf16x8*)(Ap + (wr * 32 + mi * 16 + lr) * 128 + kb);
            #pragma unroll
            for (int ni = 0; ni < 4; ++ni)
                bfr[ni] = *(const bf16x8*)(Bp + (wc * 64 + ni * 16 + lr) * 128 + kb);
            #pragma unroll
            for (int mi = 0; mi < 2; ++mi)
                #pragma unroll
                for (int ni = 0; ni < 4; ++ni)
                    acc[mi][ni] = __builtin_amdgcn_mfma_f32_16x16x32_bf16(
                        af[mi], bfr[ni], acc[mi][ni], 0, 0, 0);
        }
    }

    const float sf = sigf_s;
    #pragma unroll
    for (int mi = 0; mi < 2; ++mi) {
        int row0 = wr * 32 + mi * 16 + lg * 4;
        #pragma unroll
        for (int ni = 0; ni < 4; ++ni) {
            int col = wc * 64 + ni * 16 + lr;
            float hz = hxz[128 + col];
            size_t obase = (size_t)(tR * 128 + row0) * MCOLS + (size_t)(tC * 128 + col);
            #pragma unroll
            for (int j = 0; j < 4; ++j) {
                float arg = acc[mi][ni][j] - (hxz[row0 + j] + hz);
                out[obase + (size_t)j * MCOLS] = sf * __expf(arg);
            }
        }
    }
}

extern "C" void kernel_launch(void* const* d_in, const int* in_sizes, int n_in,
                              void* d_out, int out_size, void* d_ws, size_t ws_size,
                              hipStream_t stream) {
    const float* X = (const float*)d_in[0];
    const float* Z = (const float*)d_in[1];
    const float* l = (const float*)d_in[2];
    const float* s = (const float*)d_in[3];
    float* out = (float*)d_out;
    if (ws_size >= WS_NEED && d_ws != nullptr) {
        char* ws = (char*)d_ws;
        rbf_prep<<<512, 256, 0, stream>>>(X, Z, l, ws);
        rbf_main<<<4096, 256, 0, stream>>>(s, ws, out);
    } else {
        dim3 grid(MCOLS / 128, NROWS / 128);
        rbf_fused<<<grid, dim3(512), 0, stream>>>(X, Z, l, s, out);
    }
}

// Round 4
// 58.433 us; speedup vs baseline: 2.0825x; 2.0825x over previous
//
#include <hip/hip_runtime.h>
#include <hip/hip_bf16.h>

#define NROWS 8192
#define MCOLS 8192
#define DK    64

typedef _Float16 f16x8 __attribute__((ext_vector_type(8)));
typedef __attribute__((ext_vector_type(8))) short bf16x8;
typedef __attribute__((ext_vector_type(4))) float f32x4;

// ws layout: Xh@0 (1MB fp16 [8192][64]), Zh@1M, hx@2M (8192 f32 = 0.5*|Xs|^2,
// computed from the ROUNDED fp16 values for consistency), hz@2M+32K
#define WS_XH 0u
#define WS_ZH (1u << 20)
#define WS_HX (2u << 20)
#define WS_HZ ((2u << 20) + 32768u)
#define WS_NEED ((size_t)(2u << 20) + 65536u)

__device__ __forceinline__ float softplus_f(float x) {
    // matches jnp.where(x > 36, x, log1p(exp(min(x, 36))))
    return x > 36.0f ? x : log1pf(expf(fminf(x, 36.0f)));
}

// ---------------- prep: scale by w=1/softplus(l), round to fp16, norms ------
// 131072 threads: one per (matrix, row, kchunk-of-8). X first 65536, then Z.
// Norms use the rounded values so dist == |xh-zh|^2 exactly (error ~2^-24).
__global__ void rbf_prep(const float* __restrict__ X, const float* __restrict__ Z,
                         const float* __restrict__ lraw, char* __restrict__ ws) {
    __shared__ float wsc[DK];
    if (threadIdx.x < DK) wsc[threadIdx.x] = 1.0f / softplus_f(lraw[threadIdx.x]);
    __syncthreads();

    int tid = blockIdx.x * 256 + threadIdx.x;   // 0..131071
    bool isZ = tid >= 65536;                    // wave-uniform (65536 % 64 == 0)
    int t = tid & 65535;
    int row = t >> 3;
    int kc = t & 7;
    const float* src = (isZ ? Z : X) + (size_t)row * DK + kc * 8;
    float4 v0 = *(const float4*)(src);
    float4 v1 = *(const float4*)(src + 4);
    float f[8] = {v0.x, v0.y, v0.z, v0.w, v1.x, v1.y, v1.z, v1.w};
    f16x8 hv;
    float sq = 0.0f;
    #pragma unroll
    for (int j = 0; j < 8; ++j) {
        _Float16 h = (_Float16)(f[j] * wsc[kc * 8 + j]);
        hv[j] = h;
        float hf = (float)h;
        sq += hf * hf;
    }
    sq += __shfl_xor(sq, 1);
    sq += __shfl_xor(sq, 2);
    sq += __shfl_xor(sq, 4);
    *(f16x8*)(ws + (isZ ? WS_ZH : WS_XH) + (size_t)row * 128 + kc * 16) = hv;
    if (kc == 0) {
        float* nrm = (float*)(ws + (isZ ? WS_HZ : WS_HX));
        nrm[row] = 0.5f * sq;
    }
}

// ---------------- main: 128x128 tile, 8 waves (4x2), wave = 32x64 -----------
// Staging is a pure 32KB coalesced copy of pre-converted fp16 panels
// (conversion VALU moved to prep); single MFMA pass (fp16 products are exact
// in fp32). Epilogue (exp + stores) now dominates wave time -> high store
// duty cycle.
__launch_bounds__(512, 4)
__global__ void rbf_main(const float* __restrict__ sraw, const char* __restrict__ ws,
                         float* __restrict__ out) {
    // LDS: A [128 rows][128 B] @0, B @16K; XOR swizzle (row&7)<<4 on byte off
    __shared__ __align__(16) char smem[32768];

    // XCD-bijective swizzle: 4096 blocks, 8 XCDs, 512 contiguous per XCD
    int bid = blockIdx.x;
    int s = (bid & 7) * 512 + (bid >> 3);
    int tR = s >> 6, tC = s & 63;

    const int tid = threadIdx.x;
    const float sf = softplus_f(sraw[0]);

    // ---- stage: 512 threads x 4 chunks of 16B = 32KB ----
    #pragma unroll
    for (int c = 0; c < 4; ++c) {
        int o = c * 8192 + tid * 16;          // 0..32767
        bool isB = o >= 16384;
        int oo = o & 16383;
        int row = oo >> 7;                    // 0..127
        int colb = oo & 127;
        const char* src = ws + (isB ? WS_ZH : WS_XH)
                        + (size_t)((isB ? tC : tR) * 128 + row) * 128 + colb;
        float4 v = *(const float4*)(src);
        int dst = (isB ? 16384 : 0) + row * 128 + (colb ^ ((row & 7) << 4));
        *(float4*)(smem + dst) = v;
    }
    __syncthreads();

    // ---- MFMA: wave (wr,wc) computes rows wr*32..+32, cols wc*64..+64 ----
    const int lane = tid & 63;
    const int wid  = tid >> 6;
    const int wr = wid >> 1;         // 0..3
    const int wc = wid & 1;          // 0..1
    const int lr = lane & 15;
    const int lg = lane >> 4;
    const int swz = (lr & 7) << 4;

    f32x4 acc[2][4];
    #pragma unroll
    for (int a = 0; a < 2; ++a)
        #pragma unroll
        for (int b = 0; b < 4; ++b) acc[a][b] = f32x4{0.f, 0.f, 0.f, 0.f};

    #pragma unroll
    for (int ks = 0; ks < 2; ++ks) {
        int kb = ((lg * 16 + ks * 64) ^ swz);
        f16x8 af[2], bfr[4];
        #pragma unroll
        for (int mi = 0; mi < 2; ++mi)
            af[mi] = *(const f16x8*)(smem + (wr * 32 + mi * 16 + lr) * 128 + kb);
        #pragma unroll
        for (int ni = 0; ni < 4; ++ni)
            bfr[ni] = *(const f16x8*)(smem + 16384 + (wc * 64 + ni * 16 + lr) * 128 + kb);
        #pragma unroll
        for (int mi = 0; mi < 2; ++mi)
            #pragma unroll
            for (int ni = 0; ni < 4; ++ni)
                acc[mi][ni] = __builtin_amdgcn_mfma_f32_16x16x32_f16(
                    af[mi], bfr[ni], acc[mi][ni], 0, 0, 0);
    }

    // ---- epilogue: out = sf * exp(cross - 0.5|x|^2 - 0.5|z|^2) ----
    const float* hx = (const float*)(ws + WS_HX);
    const float* hz = (const float*)(ws + WS_HZ);
    #pragma unroll
    for (int mi = 0; mi < 2; ++mi) {
        int grow0 = tR * 128 + wr * 32 + mi * 16 + lg * 4;   // col=lane&15, row=lg*4+j
        float4 hxv = *(const float4*)(hx + grow0);
        float hxa[4] = {hxv.x, hxv.y, hxv.z, hxv.w};
        #pragma unroll
        for (int ni = 0; ni < 4; ++ni) {
            int gcol = tC * 128 + wc * 64 + ni * 16 + lr;
            float hzv = hz[gcol];
            size_t obase = (size_t)grow0 * MCOLS + gcol;
            #pragma unroll
            for (int j = 0; j < 4; ++j)
                out[obase + (size_t)j * MCOLS] = sf * __expf(acc[mi][ni][j] - hxa[j] - hzv);
        }
    }
}

// ---------------- fallback (R2 kernel, bf16 hi/lo) if ws too small ----------
__launch_bounds__(512, 4)
__global__ void rbf_fused(const float* __restrict__ X, const float* __restrict__ Z,
                          const float* __restrict__ lraw, const float* __restrict__ sraw,
                          float* __restrict__ out) {
    __shared__ __align__(16) char smem[65536];
    __shared__ float hxz[256];
    __shared__ float wsc[DK];
    __shared__ float sigf_s;

    const int tid = threadIdx.x;
    const int tR = blockIdx.y;
    const int tC = blockIdx.x;

    if (tid < DK) wsc[tid] = 1.0f / softplus_f(lraw[tid]);
    if (tid == 511) sigf_s = softplus_f(sraw[0]);
    __syncthreads();

    #pragma unroll
    for (int i = 0; i < 4; ++i) {
        int rfull = i * 64 + (tid >> 3);
        int r = rfull & 127;
        int kc = tid & 7;
        bool isB = rfull >= 128;
        const float* src = isB ? (Z + (size_t)(tC * 128 + r) * DK + kc * 8)
                               : (X + (size_t)(tR * 128 + r) * DK + kc * 8);
        float4 v0 = *(const float4*)(src);
        float4 v1 = *(const float4*)(src + 4);
        float f[8] = {v0.x, v0.y, v0.z, v0.w, v1.x, v1.y, v1.z, v1.w};
        bf16x8 hv, lv;
        float sq = 0.0f;
        #pragma unroll
        for (int j = 0; j < 8; ++j) {
            float fv = f[j] * wsc[kc * 8 + j];
            sq += fv * fv;
            unsigned int u = __float_as_uint(fv);
            u += 0x7fffu + ((u >> 16) & 1u);
            unsigned short h = (unsigned short)(u >> 16);
            hv[j] = (short)h;
            float hf = __uint_as_float(((unsigned int)h) << 16);
            unsigned int u2 = __float_as_uint(fv - hf);
            u2 += 0x7fffu + ((u2 >> 16) & 1u);
            lv[j] = (short)(unsigned short)(u2 >> 16);
        }
        sq += __shfl_xor(sq, 1);
        sq += __shfl_xor(sq, 2);
        sq += __shfl_xor(sq, 4);
        if (kc == 0) hxz[rfull] = 0.5f * sq;
        int halfOff = isB ? 32768 : 0;
        int byteOff = r * 128 + ((kc * 16) ^ ((r & 7) << 4));
        *(bf16x8*)(smem + halfOff + byteOff) = hv;
        *(bf16x8*)(smem + halfOff + 16384 + byteOff) = lv;
    }
    __syncthreads();

    const int lane = tid & 63;
    const int wid  = tid >> 6;
    const int wr = wid >> 1;
    const int wc = wid & 1;
    const int lr = lane & 15;
    const int lg = lane >> 4;
    const int swz = (lr & 7) << 4;

    f32x4 acc[2][4];
    #pragma unroll
    for (int a = 0; a < 2; ++a)
        #pragma unroll
        for (int b = 0; b < 4; ++b) acc[a][b] = f32x4{0.f, 0.f, 0.f, 0.f};

    #pragma unroll
    for (int pass = 0; pass < 3; ++pass) {
        const char* Ap = smem + ((pass == 2) ? 16384 : 0);
        const char* Bp = smem + 32768 + ((pass == 1) ? 16384 : 0);
        #pragma unroll
        for (int ks = 0; ks < 2; ++ks) {
            int kb = ((lg * 16 + ks * 64) ^ swz);
            bf16x8 af[2], bfr[4];
            #pragma unroll
            for (int mi = 0; mi < 2; ++mi)
                af[mi] = *(const bf16x8*)(Ap + (wr * 32 + mi * 16 + lr) * 128 + kb);
            #pragma unroll
            for (int ni = 0; ni < 4; ++ni)
                bfr[ni] = *(const bf16x8*)(Bp + (wc * 64 + ni * 16 + lr) * 128 + kb);
            #pragma unroll
            for (int mi = 0; mi < 2; ++mi)
                #pragma unroll
                for (int ni = 0; ni < 4; ++ni)
                    acc[mi][ni] = __builtin_amdgcn_mfma_f32_16x16x32_bf16(
                        af[mi], bfr[ni], acc[mi][ni], 0, 0, 0);
        }
    }

    const float sf = sigf_s;
    #pragma unroll
    for (int mi = 0; mi < 2; ++mi) {
        int row0 = wr * 32 + mi * 16 + lg * 4;
        #pragma unroll
        for (int ni = 0; ni < 4; ++ni) {
            int col = wc * 64 + ni * 16 + lr;
            float hzv = hxz[128 + col];
            size_t obase = (size_t)(tR * 128 + row0) * MCOLS + (size_t)(tC * 128 + col);
            #pragma unroll
            for (int j = 0; j < 4; ++j) {
                float arg = acc[mi][ni][j] - (hxz[row0 + j] + hzv);
                out[obase + (size_t)j * MCOLS] = sf * __expf(arg);
            }
        }
    }
}

extern "C" void kernel_launch(void* const* d_in, const int* in_sizes, int n_in,
                              void* d_out, int out_size, void* d_ws, size_t ws_size,
                              hipStream_t stream) {
    const float* X = (const float*)d_in[0];
    const float* Z = (const float*)d_in[1];
    const float* l = (const float*)d_in[2];
    const float* s = (const float*)d_in[3];
    float* out = (float*)d_out;
    if (ws_size >= WS_NEED && d_ws != nullptr) {
        char* ws = (char*)d_ws;
        rbf_prep<<<512, 256, 0, stream>>>(X, Z, l, ws);
        rbf_main<<<4096, 512, 0, stream>>>(s, ws, out);
    } else {
        dim3 grid(MCOLS / 128, NROWS / 128);
        rbf_fused<<<grid, dim3(512), 0, stream>>>(X, Z, l, s, out);
    }
}